// Round 17
// baseline (196.433 us; speedup 1.0000x reference)
//
#include <hip/hip_runtime.h>

#define B_   4
#define NB_  128
#define BS_  128
#define C_   256
#define H_   8
#define KL_  129   // BS_+1
#define SC2_   0.25503486f           // (1/sqrt(32)) * log2(e)
#define LOG2E_ 1.4426950408889634f
#define RSTR_  99072                 // KL_*768: u16 stride of one block in qkv

typedef unsigned short u16;
typedef unsigned int   u32;
typedef short          s16;
typedef __attribute__((ext_vector_type(8))) __bf16 bf16x8;
typedef __attribute__((ext_vector_type(4))) float  f32x4;

__device__ __forceinline__ float bf16tof(u16 u) {
  union { u32 i; float f; } v; v.i = ((u32)u) << 16; return v.f;
}
__device__ __forceinline__ u16 fbits(float a) {
  union { __bf16 h; u16 u; } v; v.h = (__bf16)a; return v.u;
}
__device__ __forceinline__ u32 pk2(float a, float b) {
  union { __bf16 h[2]; u32 u; } v;
  v.h[0] = (__bf16)a; v.h[1] = (__bf16)b;
  return v.u;
}
__device__ __forceinline__ float asf(u32 u) {
  union { u32 i; float f; } v; v.i = u; return v.f;
}

__device__ __forceinline__ void glds16(const void* g, void* l) {
  __builtin_amdgcn_global_load_lds(
      (const __attribute__((address_space(1))) unsigned int*)g,
      (__attribute__((address_space(3))) unsigned int*)l, 16, 0, 0);
}

// ---------- kernel 1: fused per-block mean + f32->bf16 convert ----------
__global__ __launch_bounds__(256) void meancvt_kernel(const float* __restrict__ x,
                                                      u16* __restrict__ xb) {
  const int blk = blockIdx.x;
  const int c = threadIdx.x;
  const float* p = x + (size_t)blk * BS_ * C_ + c;
  u16* q = xb + (size_t)blk * (KL_ * C_) + c;
  float s = 0.f;
  #pragma unroll 4
  for (int r = 0; r < BS_; ++r) {
    const float v = p[(size_t)r * C_];
    s += v;
    q[(size_t)r * C_] = fbits(v);
  }
  q[(size_t)BS_ * C_] = fbits(s * (1.0f / BS_));
}

// ---------- kernel 2: transpose+convert weights ----------
__global__ __launch_bounds__(256) void wt_kernel(const float* __restrict__ wq,
      const float* __restrict__ wp, s16* __restrict__ wtq, s16* __restrict__ wtp) {
  const int i = blockIdx.x * 256 + threadIdx.x;
  if (i < 768 * 256) {
    const int nn = i >> 8, k = i & 255;
    wtq[i] = (s16)fbits(wq[k * 768 + nn]);
  } else {
    const int j = i - 768 * 256;
    const int nn = j >> 8, k = j & 255;
    wtp[j] = (s16)fbits(wp[k * 256 + nn]);
  }
}

// ---------- kernel 4: gate/sadd table precompute ----------
// g4t[n][h][q][k<128] = bf16 gate coeff (mask/diag baked; 0 when masked).
// s4t[n][q][k<128]    = bf16 (e3*log2e; -1e30 when masked). s4t lives in
// d_out scratch (overwritten by the final GEMM). Key 128 handled in attn.
__global__ __launch_bounds__(256) void pre_kernel(const int* __restrict__ mask,
      const float* __restrict__ ef, const float* __restrict__ wg_,
      const float* __restrict__ bg, u16* __restrict__ g4t,
      u16* __restrict__ s4t) {
  const int t = blockIdx.x * 256 + threadIdx.x;   // (n*128+q)*32 + kq
  const int kq = t & 31;
  const int row = t >> 5;                          // n*128+q
  const int n = row >> 7;
  const int q = row & 127;
  const int key0 = kq * 4;
  const int* mrow = mask + (size_t)row * KL_;
  const float* erow = ef + (size_t)row * KL_ * 4;
  float e0[4], e1[4], e2[4], e3[4];
  int m[4];
  #pragma unroll
  for (int r = 0; r < 4; ++r) {
    const int key = key0 + r;
    m[r] = mrow[key];
    float4 ev = *(const float4*)(erow + (size_t)key * 4);
    if (key == q) { ev.x = 0.f; ev.y = 0.f; ev.z = 0.f; ev.w = 1.f; }
    e0[r] = ev.x; e1[r] = ev.y; e2[r] = ev.z; e3[r] = ev.w;
  }
  float s[4];
  #pragma unroll
  for (int r = 0; r < 4; ++r) s[r] = m[r] ? e3[r] * LOG2E_ : -1e30f;
  *(uint2*)(s4t + (size_t)row * 128 + key0) =
      uint2{pk2(s[0], s[1]), pk2(s[2], s[3])};
  #pragma unroll
  for (int h = 0; h < 8; ++h) {
    const float w0 = wg_[h], w1 = wg_[8 + h], w2 = wg_[16 + h],
                w3 = wg_[24 + h], bh = bg[h];
    float gt[4];
    #pragma unroll
    for (int r = 0; r < 4; ++r) {
      const float gg = fmaf(e0[r], w0, fmaf(e1[r], w1,
                        fmaf(e2[r], w2, fmaf(e3[r], w3, bh))));
      gt[r] = m[r] ? gg : 0.f;
    }
    *(uint2*)(g4t + (((size_t)n * 8 + h) * 128 + q) * 128 + key0) =
        uint2{pk2(gt[0], gt[1]), pk2(gt[2], gt[3])};
  }
}

// ---------- kernels 3 & 6: MFMA bf16 GEMM, 2-phase dbuf, XCD-swizzled ------
// 1D grid, nwg % 8 == 0; g=(bid&7)*(nwg/8)+(bid>>3): each XCD owns a
// contiguous row range, ncol column-tiles of a row consecutive on one XCD
// -> A-panel fetched from HBM once, L2-hit (ncol-1)x.
// STRIDED: A bf16 from qkv K-plane: row -> qkv + row*RSTR_ + r*768 + 256.
template<bool STRIDED, bool OBF16, int NS>
__global__ __launch_bounds__(256) void mfma_gemm(const s16* __restrict__ Ab,
      const s16* __restrict__ Bt, const float* __restrict__ bias,
      void* __restrict__ outv) {
  __shared__ __align__(16) s16 Al[2][128 * 64];
  __shared__ __align__(16) s16 Bl[2][128 * 64];
  const int tid = threadIdx.x;
  const int lane = tid & 63;
  const int wid = tid >> 6;
  constexpr int ncol = NS / 128;
  const int per  = gridDim.x >> 3;
  const int gidx = (blockIdx.x & 7) * per + (blockIdx.x >> 3);
  const int arow = gidx / ncol;
  const int col0 = (gidx - arow * ncol) * 128;
  const int row0 = arow * 128;
  const int ldrow = lane >> 3;
  const int lcb   = (lane & 7) * 16;

  auto STAGE = [&](int k0, int buf) {
    #pragma unroll
    for (int j = 0; j < 4; ++j) {
      const int c = wid * 4 + j;
      const int row = c * 8 + ldrow;
      const int scb = lcb ^ ((row & 7) << 4);
      glds16(Bt + (size_t)(col0 + row) * C_ + k0 + (scb >> 1), &Bl[buf][c * 512]);
    }
    #pragma unroll
    for (int j = 0; j < 4; ++j) {
      const int c = wid * 4 + j;
      const int row = c * 8 + ldrow;
      const int scb = lcb ^ ((row & 7) << 4);
      if constexpr (STRIDED)
        glds16(Ab + (size_t)arow * RSTR_ + (size_t)row * 768 + 256
                  + k0 + (scb >> 1), &Al[buf][c * 512]);
      else
        glds16(Ab + (size_t)(row0 + row) * C_ + k0 + (scb >> 1), &Al[buf][c * 512]);
    }
  };

  f32x4 acc[4][4];
  #pragma unroll
  for (int i = 0; i < 4; ++i)
    #pragma unroll
    for (int j = 0; j < 4; ++j) acc[i][j] = f32x4{0.f, 0.f, 0.f, 0.f};

  STAGE(0, 0);
  __syncthreads();

  const int fr = lane & 15;
  const int ar0 = (wid >> 1) * 64;
  const int ac0 = (wid & 1) * 64;
  #pragma unroll 1
  for (int t = 0; t < 4; ++t) {
    if (t < 3) STAGE((t + 1) * 64, (t + 1) & 1);
    const char* Ac = (const char*)&Al[t & 1][0];
    const char* Bc = (const char*)&Bl[t & 1][0];
    #pragma unroll
    for (int kk = 0; kk < 64; kk += 32) {
      const int kb = kk * 2 + (lane >> 4) * 16;
      bf16x8 af[4], bfr[4];
      #pragma unroll
      for (int mf = 0; mf < 4; ++mf) {
        const int row = ar0 + mf * 16 + fr;
        af[mf] = *(const bf16x8*)(Ac + row * 128 + (kb ^ ((row & 7) << 4)));
      }
      #pragma unroll
      for (int nf = 0; nf < 4; ++nf) {
        const int row = ac0 + nf * 16 + fr;
        bfr[nf] = *(const bf16x8*)(Bc + row * 128 + (kb ^ ((row & 7) << 4)));
      }
      #pragma unroll
      for (int mf = 0; mf < 4; ++mf)
        #pragma unroll
        for (int nf = 0; nf < 4; ++nf)
          acc[mf][nf] = __builtin_amdgcn_mfma_f32_16x16x32_bf16(
              af[mf], bfr[nf], acc[mf][nf], 0, 0, 0);
    }
    __syncthreads();
  }

  const int orow0 = row0 + (wid >> 1) * 64 + (lane >> 4) * 4;
  const int ocol0 = col0 + (wid & 1) * 64 + (lane & 15);
  #pragma unroll
  for (int nf = 0; nf < 4; ++nf) {
    const int col = ocol0 + nf * 16;
    const float bb = bias[col];
    #pragma unroll
    for (int mf = 0; mf < 4; ++mf) {
      #pragma unroll
      for (int r = 0; r < 4; ++r) {
        const size_t row = (size_t)(orow0 + mf * 16 + r);
        const float v = acc[mf][nf][r] + bb;
        if constexpr (OBF16) ((u16*)outv)[row * NS + col] = fbits(v);
        else                 ((float*)outv)[row * NS + col] = v;
      }
    }
  }
}

// ---------- kernel 5: MFMA fused block attention (interleaved PV) ----------
// Round-16 structure (K/V^T staged in LDS, two-phase PV, g4t/s4t tables)
// with ONE change: PV(w) chunk c is issued right after its two producer
// f-iterations (f=2c,2c+1) instead of after the whole phase A. PV(w) needs
// no psum (normalization is post-PV via shfl(inv)), and in lockstep the
// wave's P keys 32c..32c+31 are complete after f=2c+1 -> the MFMA-pipe PV
// overlaps the next iterations' exp2 VALU chain, and the single big
// lgkmcnt drain becomes four small early ones. Key-128 QK MFMA hoisted to
// the top of the mt (consumed only at psum time). P tile is wave-private ->
// reorder is race-free.
__global__ __launch_bounds__(256, 4) void attn_kernel(u16* __restrict__ qkv,
      const u16* __restrict__ g4t, const u16* __restrict__ s4t,
      const float* __restrict__ wg_, const float* __restrict__ bg) {
  __shared__ __align__(16) char lds[36176];  // K 10320 + V^T 8448 + 4x P 4352
  const int bid = blockIdx.x;
  const int xcd = bid & 7;
  const int j   = bid >> 3;                  // 0..511
  const int wgi = xcd * 64 + (j >> 3);       // b*NB_ + n  (64 blocks per XCD)
  const int h   = j & 7;                     // WG-uniform head
  const int n = wgi & (NB_ - 1);
  const int tid = threadIdx.x;
  const int wid = tid >> 6, lane = tid & 63;
  const int g = lane >> 4, ql = lane & 15;
  u16*  Kl = (u16*)lds;                      // [129][40] u16 (rows padded)
  u16*  vt = (u16*)(lds + 10320);            // [32 d][132 keys] u16
  char* pb = lds + 18768 + wid * 4352;       // per-wave P: 16 rows x 272 B

  u16* qkv_blk = qkv + (size_t)wgi * RSTR_;
  const u16* sbase = s4t + (size_t)n * (128 * 128);
  const u16* gbase = g4t + ((size_t)n * 8 + h) * (128 * 128);

  // cooperative stage: K rows (64B each) into padded LDS rows
  for (int i = tid; i < 516; i += 256) {
    const int r = i >> 2, dc = i & 3;
    const uint4 u = *(const uint4*)(qkv_blk + (size_t)r * 768 + 256 + h * 32 + dc * 8);
    *(uint4*)(Kl + r * 40 + dc * 8) = u;
  }
  // cooperative stage: V^T keys 0..127 (transposed scalar writes)
  for (int i = tid; i < 512; i += 256) {
    const int r = i >> 2, dc = i & 3;
    const uint4 u = *(const uint4*)(qkv_blk + (size_t)r * 768 + 512 + h * 32 + dc * 8);
    u16* col = vt + (dc * 8) * 132 + r;
    col[0 * 132] = (u16)(u.x & 0xffff); col[1 * 132] = (u16)(u.x >> 16);
    col[2 * 132] = (u16)(u.y & 0xffff); col[3 * 132] = (u16)(u.y >> 16);
    col[4 * 132] = (u16)(u.z & 0xffff); col[5 * 132] = (u16)(u.z >> 16);
    col[6 * 132] = (u16)(u.w & 0xffff); col[7 * 132] = (u16)(u.w >> 16);
  }
  __syncthreads();

  // key-128 V values for this lane's two output columns
  const float v128a = bf16tof(qkv_blk[(size_t)128 * 768 + 512 + h * 32 + ql]);
  const float v128b = bf16tof(qkv_blk[(size_t)128 * 768 + 512 + h * 32 + 16 + ql]);
  const float gk128 = wg_[24 + h] + bg[h];   // key-128 gate (always unmasked)

  #pragma unroll 1
  for (int mi = 0; mi < 2; ++mi) {
    const int mt = wid * 2 + mi;
    const int qrow = mt * 16 + ql;
    const bf16x8 qf = *(const bf16x8*)(qkv_blk + (size_t)qrow * 768 + h * 32 + g * 8);
    const u16* srow = sbase + (size_t)qrow * 128;
    const u16* grow = gbase + (size_t)qrow * 128;

    // key-128 QK logit issued up front (consumed only at psum time)
    const bf16x8 kf8 = *(const bf16x8*)(Kl + 128 * 40 + 8 * g);
    f32x4 st8 = __builtin_amdgcn_mfma_f32_16x16x32_bf16(
        kf8, qf, f32x4{0.f, 0.f, 0.f, 0.f}, 0, 0, 0);

    // ---- phase A with interleaved PV(w): for each chunk c, produce the
    //      P keys (f=2c,2c+1) then immediately consume them with 2 MFMAs ----
    float psum = 0.f;
    uint2 gab[8];
    f32x4 ow0{0.f,0.f,0.f,0.f}, ow1{0.f,0.f,0.f,0.f};
    #pragma unroll
    for (int c = 0; c < 4; ++c) {
      #pragma unroll
      for (int ff = 0; ff < 2; ++ff) {
        const int f = 2 * c + ff;
        const bf16x8 kf = *(const bf16x8*)(Kl + (16 * f + ql) * 40 + 8 * g);
        f32x4 st = __builtin_amdgcn_mfma_f32_16x16x32_bf16(
            kf, qf, f32x4{0.f, 0.f, 0.f, 0.f}, 0, 0, 0);
        const uint2 sv = *(const uint2*)(srow + 16 * f + 4 * g);
        gab[f] = *(const uint2*)(grow + 16 * f + 4 * g);
        float w[4];
        w[0] = __builtin_amdgcn_exp2f(fmaf(st[0], SC2_, asf(sv.x << 16)));
        w[1] = __builtin_amdgcn_exp2f(fmaf(st[1], SC2_, asf(sv.x & 0xffff0000u)));
        w[2] = __builtin_amdgcn_exp2f(fmaf(st[2], SC2_, asf(sv.y << 16)));
        w[3] = __builtin_amdgcn_exp2f(fmaf(st[3], SC2_, asf(sv.y & 0xffff0000u)));
        psum += (w[0] + w[1]) + (w[2] + w[3]);
        *(uint2*)(pb + ql * 272 + (16 * f + 4 * g) * 2) =
            uint2{pk2(w[0], w[1]), pk2(w[2], w[3])};
      }
      // PV(w) chunk c (keys 32c..32c+31 complete for the whole wave)
      const bf16x8 pa = *(const bf16x8*)(pb + ql * 272 + (32 * c + 8 * g) * 2);
      const bf16x8 v0 = *(const bf16x8*)(vt + ql * 132 + 32 * c + 8 * g);
      const bf16x8 v1 = *(const bf16x8*)(vt + (16 + ql) * 132 + 32 * c + 8 * g);
      ow0 = __builtin_amdgcn_mfma_f32_16x16x32_bf16(pa, v0, ow0, 0, 0, 0);
      ow1 = __builtin_amdgcn_mfma_f32_16x16x32_bf16(pa, v1, ow1, 0, 0, 0);
    }
    // key 128 (always unmasked)
    const float w0 = __builtin_amdgcn_exp2f(
        fmaf(st8[0], SC2_, (g == 0) ? LOG2E_ : -1e30f));
    psum += w0;
    psum += __shfl_xor(psum, 16);
    psum += __shfl_xor(psum, 32);
    const float inv = __builtin_amdgcn_rcpf(psum);
    const float c128 = fmaf(w0, inv, (g == 0) ? gk128 : 0.f);

    // ---- phase B: gate pass through the same P tile (prepacked words) ----
    #pragma unroll
    for (int f = 0; f < 8; ++f)
      *(uint2*)(pb + ql * 272 + (16 * f + 4 * g) * 2) = gab[f];
    f32x4 og0{0.f,0.f,0.f,0.f}, og1{0.f,0.f,0.f,0.f};
    #pragma unroll
    for (int c = 0; c < 4; ++c) {
      const bf16x8 pa = *(const bf16x8*)(pb + ql * 272 + (32 * c + 8 * g) * 2);
      const bf16x8 v0 = *(const bf16x8*)(vt + ql * 132 + 32 * c + 8 * g);
      const bf16x8 v1 = *(const bf16x8*)(vt + (16 + ql) * 132 + 32 * c + 8 * g);
      og0 = __builtin_amdgcn_mfma_f32_16x16x32_bf16(pa, v0, og0, 0, 0, 0);
      og1 = __builtin_amdgcn_mfma_f32_16x16x32_bf16(pa, v1, og1, 0, 0, 0);
    }
    // ---- normalize (PV rows are q=4g+r -> shfl inv/c128) and store ----
    u16* aop = qkv_blk + (size_t)(mt * 16 + g * 4) * 768 + 256 + h * 32 + ql;
    #pragma unroll
    for (int r = 0; r < 4; ++r) {
      const float iv = __shfl(inv,  4 * g + r);
      const float cc = __shfl(c128, 4 * g + r);
      aop[(size_t)r * 768]      = fbits(fmaf(cc, v128a, fmaf(ow0[r], iv, og0[r])));
      aop[(size_t)r * 768 + 16] = fbits(fmaf(cc, v128b, fmaf(ow1[r], iv, og1[r])));
    }
  }
}

extern "C" void kernel_launch(void* const* d_in, const int* in_sizes, int n_in,
                              void* d_out, int out_size, void* d_ws, size_t ws_size,
                              hipStream_t stream) {
  (void)in_sizes; (void)n_in; (void)out_size; (void)ws_size;
  const float* x      = (const float*)d_in[0];
  const int*   mask   = (const int*)  d_in[1];
  const float* ef     = (const float*)d_in[2];
  const float* w_qkv  = (const float*)d_in[3];
  const float* b_qkv  = (const float*)d_in[4];
  const float* w_proj = (const float*)d_in[5];
  const float* b_proj = (const float*)d_in[6];
  const float* w_gate = (const float*)d_in[7];
  const float* b_gate = (const float*)d_in[8];
  float* out = (float*)d_out;
  char* ws = (char*)d_ws;

  // workspace layout (bytes), total 135,790,592 (<= proven 136,052,736)
  u16* qkv = (u16*)(ws);                     //   101,449,728
  s16* wtq = (s16*)(ws + 101449728);         //       393,216
  s16* wtp = (s16*)(ws + 101842944);         //       131,072
  u16* xb  = (u16*)(ws + 101974016);         //    33,816,576 (dead after QKV GEMM)
  u16* g4t = (u16*)(ws + 101974016);         //    33,554,432 (aliases xb; written after)
  // s4t scratch lives in d_out (4,194,304 B); final GEMM overwrites all of d_out.
  u16* s4t = (u16*)d_out;

  meancvt_kernel<<<B_ * NB_, 256, 0, stream>>>(x, xb);
  wt_kernel<<<(768 * 256 + 256 * 256) / 256, 256, 0, stream>>>(
      w_qkv, w_proj, wtq, wtp);
  mfma_gemm<false, true, 768>
      <<<(B_ * NB_ * KL_ / 128) * 6, 256, 0, stream>>>(
      (const s16*)xb, wtq, b_qkv, qkv);
  pre_kernel<<<(NB_ * BS_ * 32) / 256, 256, 0, stream>>>(
      mask, ef, w_gate, b_gate, g4t, s4t);
  attn_kernel<<<B_ * NB_ * H_, 256, 0, stream>>>(
      qkv, (const u16*)g4t, (const u16*)s4t, w_gate, b_gate);
  mfma_gemm<true, false, 256>
      <<<(B_ * NB_ * BS_ / 128) * 2, 256, 0, stream>>>(
      (const s16*)qkv, wtp, b_proj, out);
}

// Round 18
// 189.467 us; speedup vs baseline: 1.0368x; 1.0368x over previous
//
#include <hip/hip_runtime.h>

#define B_   4
#define NB_  128
#define BS_  128
#define C_   256
#define H_   8
#define KL_  129   // BS_+1
#define SC2_   0.25503486f           // (1/sqrt(32)) * log2(e)
#define LOG2E_ 1.4426950408889634f
#define RSTR_  99072                 // KL_*768: u16 stride of one block in qkv

typedef unsigned short u16;
typedef unsigned int   u32;
typedef short          s16;
typedef __attribute__((ext_vector_type(8))) __bf16 bf16x8;
typedef __attribute__((ext_vector_type(4))) float  f32x4;

__device__ __forceinline__ float bf16tof(u16 u) {
  union { u32 i; float f; } v; v.i = ((u32)u) << 16; return v.f;
}
__device__ __forceinline__ u16 fbits(float a) {
  union { __bf16 h; u16 u; } v; v.h = (__bf16)a; return v.u;
}
__device__ __forceinline__ u32 pk2(float a, float b) {
  union { __bf16 h[2]; u32 u; } v;
  v.h[0] = (__bf16)a; v.h[1] = (__bf16)b;
  return v.u;
}
__device__ __forceinline__ float asf(u32 u) {
  union { u32 i; float f; } v; v.i = u; return v.f;
}

__device__ __forceinline__ void glds16(const void* g, void* l) {
  __builtin_amdgcn_global_load_lds(
      (const __attribute__((address_space(1))) unsigned int*)g,
      (__attribute__((address_space(3))) unsigned int*)l, 16, 0, 0);
}

// ---------- kernel 1: fused per-block mean + f32->bf16 convert ----------
__global__ __launch_bounds__(256) void meancvt_kernel(const float* __restrict__ x,
                                                      u16* __restrict__ xb) {
  const int blk = blockIdx.x;
  const int c = threadIdx.x;
  const float* p = x + (size_t)blk * BS_ * C_ + c;
  u16* q = xb + (size_t)blk * (KL_ * C_) + c;
  float s = 0.f;
  #pragma unroll 4
  for (int r = 0; r < BS_; ++r) {
    const float v = p[(size_t)r * C_];
    s += v;
    q[(size_t)r * C_] = fbits(v);
  }
  q[(size_t)BS_ * C_] = fbits(s * (1.0f / BS_));
}

// ---------- kernel 2: transpose+convert weights ----------
__global__ __launch_bounds__(256) void wt_kernel(const float* __restrict__ wq,
      const float* __restrict__ wp, s16* __restrict__ wtq, s16* __restrict__ wtp) {
  const int i = blockIdx.x * 256 + threadIdx.x;
  if (i < 768 * 256) {
    const int nn = i >> 8, k = i & 255;
    wtq[i] = (s16)fbits(wq[k * 768 + nn]);
  } else {
    const int j = i - 768 * 256;
    const int nn = j >> 8, k = j & 255;
    wtp[j] = (s16)fbits(wp[k * 256 + nn]);
  }
}

// ---------- kernel 4: gate/sadd table precompute ----------
// g4t[n][h][q][k<128] = bf16 gate coeff (mask/diag baked; 0 when masked).
// s4t[n][q][k<128]    = bf16 (e3*log2e; -1e30 when masked). s4t lives in
// d_out scratch (overwritten by the final GEMM). Key 128 handled in attn.
__global__ __launch_bounds__(256) void pre_kernel(const int* __restrict__ mask,
      const float* __restrict__ ef, const float* __restrict__ wg_,
      const float* __restrict__ bg, u16* __restrict__ g4t,
      u16* __restrict__ s4t) {
  const int t = blockIdx.x * 256 + threadIdx.x;   // (n*128+q)*32 + kq
  const int kq = t & 31;
  const int row = t >> 5;                          // n*128+q
  const int n = row >> 7;
  const int q = row & 127;
  const int key0 = kq * 4;
  const int* mrow = mask + (size_t)row * KL_;
  const float* erow = ef + (size_t)row * KL_ * 4;
  float e0[4], e1[4], e2[4], e3[4];
  int m[4];
  #pragma unroll
  for (int r = 0; r < 4; ++r) {
    const int key = key0 + r;
    m[r] = mrow[key];
    float4 ev = *(const float4*)(erow + (size_t)key * 4);
    if (key == q) { ev.x = 0.f; ev.y = 0.f; ev.z = 0.f; ev.w = 1.f; }
    e0[r] = ev.x; e1[r] = ev.y; e2[r] = ev.z; e3[r] = ev.w;
  }
  float s[4];
  #pragma unroll
  for (int r = 0; r < 4; ++r) s[r] = m[r] ? e3[r] * LOG2E_ : -1e30f;
  *(uint2*)(s4t + (size_t)row * 128 + key0) =
      uint2{pk2(s[0], s[1]), pk2(s[2], s[3])};
  #pragma unroll
  for (int h = 0; h < 8; ++h) {
    const float w0 = wg_[h], w1 = wg_[8 + h], w2 = wg_[16 + h],
                w3 = wg_[24 + h], bh = bg[h];
    float gt[4];
    #pragma unroll
    for (int r = 0; r < 4; ++r) {
      const float gg = fmaf(e0[r], w0, fmaf(e1[r], w1,
                        fmaf(e2[r], w2, fmaf(e3[r], w3, bh))));
      gt[r] = m[r] ? gg : 0.f;
    }
    *(uint2*)(g4t + (((size_t)n * 8 + h) * 128 + q) * 128 + key0) =
        uint2{pk2(gt[0], gt[1]), pk2(gt[2], gt[3])};
  }
}

// ---------- kernels 3 & 6: MFMA bf16 GEMM, 2-phase dbuf, XCD-swizzled ------
// 1D grid, nwg % 8 == 0; g=(bid&7)*(nwg/8)+(bid>>3): each XCD owns a
// contiguous row range, ncol column-tiles of a row consecutive on one XCD
// -> A-panel fetched from HBM once, L2-hit (ncol-1)x.
// STRIDED: A bf16 from qkv K-plane: row -> qkv + row*RSTR_ + r*768 + 256.
template<bool STRIDED, bool OBF16, int NS>
__global__ __launch_bounds__(256) void mfma_gemm(const s16* __restrict__ Ab,
      const s16* __restrict__ Bt, const float* __restrict__ bias,
      void* __restrict__ outv) {
  __shared__ __align__(16) s16 Al[2][128 * 64];
  __shared__ __align__(16) s16 Bl[2][128 * 64];
  const int tid = threadIdx.x;
  const int lane = tid & 63;
  const int wid = tid >> 6;
  constexpr int ncol = NS / 128;
  const int per  = gridDim.x >> 3;
  const int gidx = (blockIdx.x & 7) * per + (blockIdx.x >> 3);
  const int arow = gidx / ncol;
  const int col0 = (gidx - arow * ncol) * 128;
  const int row0 = arow * 128;
  const int ldrow = lane >> 3;
  const int lcb   = (lane & 7) * 16;

  auto STAGE = [&](int k0, int buf) {
    #pragma unroll
    for (int j = 0; j < 4; ++j) {
      const int c = wid * 4 + j;
      const int row = c * 8 + ldrow;
      const int scb = lcb ^ ((row & 7) << 4);
      glds16(Bt + (size_t)(col0 + row) * C_ + k0 + (scb >> 1), &Bl[buf][c * 512]);
    }
    #pragma unroll
    for (int j = 0; j < 4; ++j) {
      const int c = wid * 4 + j;
      const int row = c * 8 + ldrow;
      const int scb = lcb ^ ((row & 7) << 4);
      if constexpr (STRIDED)
        glds16(Ab + (size_t)arow * RSTR_ + (size_t)row * 768 + 256
                  + k0 + (scb >> 1), &Al[buf][c * 512]);
      else
        glds16(Ab + (size_t)(row0 + row) * C_ + k0 + (scb >> 1), &Al[buf][c * 512]);
    }
  };

  f32x4 acc[4][4];
  #pragma unroll
  for (int i = 0; i < 4; ++i)
    #pragma unroll
    for (int j = 0; j < 4; ++j) acc[i][j] = f32x4{0.f, 0.f, 0.f, 0.f};

  STAGE(0, 0);
  __syncthreads();

  const int fr = lane & 15;
  const int ar0 = (wid >> 1) * 64;
  const int ac0 = (wid & 1) * 64;
  #pragma unroll 1
  for (int t = 0; t < 4; ++t) {
    if (t < 3) STAGE((t + 1) * 64, (t + 1) & 1);
    const char* Ac = (const char*)&Al[t & 1][0];
    const char* Bc = (const char*)&Bl[t & 1][0];
    #pragma unroll
    for (int kk = 0; kk < 64; kk += 32) {
      const int kb = kk * 2 + (lane >> 4) * 16;
      bf16x8 af[4], bfr[4];
      #pragma unroll
      for (int mf = 0; mf < 4; ++mf) {
        const int row = ar0 + mf * 16 + fr;
        af[mf] = *(const bf16x8*)(Ac + row * 128 + (kb ^ ((row & 7) << 4)));
      }
      #pragma unroll
      for (int nf = 0; nf < 4; ++nf) {
        const int row = ac0 + nf * 16 + fr;
        bfr[nf] = *(const bf16x8*)(Bc + row * 128 + (kb ^ ((row & 7) << 4)));
      }
      #pragma unroll
      for (int mf = 0; mf < 4; ++mf)
        #pragma unroll
        for (int nf = 0; nf < 4; ++nf)
          acc[mf][nf] = __builtin_amdgcn_mfma_f32_16x16x32_bf16(
              af[mf], bfr[nf], acc[mf][nf], 0, 0, 0);
    }
    __syncthreads();
  }

  const int orow0 = row0 + (wid >> 1) * 64 + (lane >> 4) * 4;
  const int ocol0 = col0 + (wid & 1) * 64 + (lane & 15);
  #pragma unroll
  for (int nf = 0; nf < 4; ++nf) {
    const int col = ocol0 + nf * 16;
    const float bb = bias[col];
    #pragma unroll
    for (int mf = 0; mf < 4; ++mf) {
      #pragma unroll
      for (int r = 0; r < 4; ++r) {
        const size_t row = (size_t)(orow0 + mf * 16 + r);
        const float v = acc[mf][nf][r] + bb;
        if constexpr (OBF16) ((u16*)outv)[row * NS + col] = fbits(v);
        else                 ((float*)outv)[row * NS + col] = v;
      }
    }
  }
}

// ---------- kernel 5: MFMA fused block attention (round-16 + 2 tweaks) -----
// One WG per (block, head), h WG-uniform; XCD-aware swizzle. 4 waves;
// K[129][40] and V^T[32][134] staged cooperatively (V^T stride 132->134:
// 268B rows give staging-write dc-offsets {0,24,16,8} -> 2-way max, vs
// 264B's {0,16,0,16} 4-way); wave wid owns mt tiles {2wid,2wid+1};
// two-phase PV with s_setprio(1) around the pure-MFMA PV clusters (T5,
// m191 regime: barrier-free independent waves).
__global__ __launch_bounds__(256, 4) void attn_kernel(u16* __restrict__ qkv,
      const u16* __restrict__ g4t, const u16* __restrict__ s4t,
      const float* __restrict__ wg_, const float* __restrict__ bg) {
  __shared__ __align__(16) char lds[36304];  // K 10320 + V^T 8576 + 4x P 4352
  const int bid = blockIdx.x;
  const int xcd = bid & 7;
  const int j   = bid >> 3;                  // 0..511
  const int wgi = xcd * 64 + (j >> 3);       // b*NB_ + n  (64 blocks per XCD)
  const int h   = j & 7;                     // WG-uniform head
  const int n = wgi & (NB_ - 1);
  const int tid = threadIdx.x;
  const int wid = tid >> 6, lane = tid & 63;
  const int g = lane >> 4, ql = lane & 15;
  u16*  Kl = (u16*)lds;                      // [129][40] u16 (rows padded)
  u16*  vt = (u16*)(lds + 10320);            // [32 d][134 keys] u16
  char* pb = lds + 18896 + wid * 4352;       // per-wave P: 16 rows x 272 B

  u16* qkv_blk = qkv + (size_t)wgi * RSTR_;
  const u16* sbase = s4t + (size_t)n * (128 * 128);
  const u16* gbase = g4t + ((size_t)n * 8 + h) * (128 * 128);

  // cooperative stage: K rows (64B each) into padded LDS rows
  for (int i = tid; i < 516; i += 256) {
    const int r = i >> 2, dc = i & 3;
    const uint4 u = *(const uint4*)(qkv_blk + (size_t)r * 768 + 256 + h * 32 + dc * 8);
    *(uint4*)(Kl + r * 40 + dc * 8) = u;
  }
  // cooperative stage: V^T keys 0..127 (transposed scalar writes)
  for (int i = tid; i < 512; i += 256) {
    const int r = i >> 2, dc = i & 3;
    const uint4 u = *(const uint4*)(qkv_blk + (size_t)r * 768 + 512 + h * 32 + dc * 8);
    u16* col = vt + (dc * 8) * 134 + r;
    col[0 * 134] = (u16)(u.x & 0xffff); col[1 * 134] = (u16)(u.x >> 16);
    col[2 * 134] = (u16)(u.y & 0xffff); col[3 * 134] = (u16)(u.y >> 16);
    col[4 * 134] = (u16)(u.z & 0xffff); col[5 * 134] = (u16)(u.z >> 16);
    col[6 * 134] = (u16)(u.w & 0xffff); col[7 * 134] = (u16)(u.w >> 16);
  }
  __syncthreads();

  // key-128 V values for this lane's two output columns
  const float v128a = bf16tof(qkv_blk[(size_t)128 * 768 + 512 + h * 32 + ql]);
  const float v128b = bf16tof(qkv_blk[(size_t)128 * 768 + 512 + h * 32 + 16 + ql]);
  const float gk128 = wg_[24 + h] + bg[h];   // key-128 gate (always unmasked)

  #pragma unroll 1
  for (int mi = 0; mi < 2; ++mi) {
    const int mt = wid * 2 + mi;
    const int qrow = mt * 16 + ql;
    const bf16x8 qf = *(const bf16x8*)(qkv_blk + (size_t)qrow * 768 + h * 32 + g * 8);
    const u16* srow = sbase + (size_t)qrow * 128;
    const u16* grow = gbase + (size_t)qrow * 128;

    // ---- phase A: stream f; write UNNORMALIZED w to P; stash gate words ----
    float psum = 0.f;
    uint2 gab[8];
    #pragma unroll
    for (int f = 0; f < 8; ++f) {
      const bf16x8 kf = *(const bf16x8*)(Kl + (16 * f + ql) * 40 + 8 * g);
      f32x4 st = __builtin_amdgcn_mfma_f32_16x16x32_bf16(
          kf, qf, f32x4{0.f, 0.f, 0.f, 0.f}, 0, 0, 0);
      const uint2 sv = *(const uint2*)(srow + 16 * f + 4 * g);
      gab[f] = *(const uint2*)(grow + 16 * f + 4 * g);
      float w[4];
      w[0] = __builtin_amdgcn_exp2f(fmaf(st[0], SC2_, asf(sv.x << 16)));
      w[1] = __builtin_amdgcn_exp2f(fmaf(st[1], SC2_, asf(sv.x & 0xffff0000u)));
      w[2] = __builtin_amdgcn_exp2f(fmaf(st[2], SC2_, asf(sv.y << 16)));
      w[3] = __builtin_amdgcn_exp2f(fmaf(st[3], SC2_, asf(sv.y & 0xffff0000u)));
      psum += (w[0] + w[1]) + (w[2] + w[3]);
      *(uint2*)(pb + ql * 272 + (16 * f + 4 * g) * 2) =
          uint2{pk2(w[0], w[1]), pk2(w[2], w[3])};
    }
    // key 128 (always unmasked; broadcast row read)
    const bf16x8 kf8 = *(const bf16x8*)(Kl + 128 * 40 + 8 * g);
    f32x4 st8 = __builtin_amdgcn_mfma_f32_16x16x32_bf16(
        kf8, qf, f32x4{0.f, 0.f, 0.f, 0.f}, 0, 0, 0);
    const float w0 = __builtin_amdgcn_exp2f(
        fmaf(st8[0], SC2_, (g == 0) ? LOG2E_ : -1e30f));
    psum += w0;
    psum += __shfl_xor(psum, 16);
    psum += __shfl_xor(psum, 32);
    const float inv = __builtin_amdgcn_rcpf(psum);
    const float c128 = fmaf(w0, inv, (g == 0) ? gk128 : 0.f);

    // ---- PV over unnormalized w (pure MFMA cluster: setprio) ----
    f32x4 ow0{0.f,0.f,0.f,0.f}, ow1{0.f,0.f,0.f,0.f};
    __builtin_amdgcn_s_setprio(1);
    #pragma unroll
    for (int c = 0; c < 4; ++c) {
      const bf16x8 pa = *(const bf16x8*)(pb + ql * 272 + (32 * c + 8 * g) * 2);
      const bf16x8 v0 = *(const bf16x8*)(vt + ql * 134 + 32 * c + 8 * g);
      const bf16x8 v1 = *(const bf16x8*)(vt + (16 + ql) * 134 + 32 * c + 8 * g);
      ow0 = __builtin_amdgcn_mfma_f32_16x16x32_bf16(pa, v0, ow0, 0, 0, 0);
      ow1 = __builtin_amdgcn_mfma_f32_16x16x32_bf16(pa, v1, ow1, 0, 0, 0);
    }
    __builtin_amdgcn_s_setprio(0);
    // ---- phase B: gate pass through the same P tile (prepacked words) ----
    #pragma unroll
    for (int f = 0; f < 8; ++f)
      *(uint2*)(pb + ql * 272 + (16 * f + 4 * g) * 2) = gab[f];
    f32x4 og0{0.f,0.f,0.f,0.f}, og1{0.f,0.f,0.f,0.f};
    __builtin_amdgcn_s_setprio(1);
    #pragma unroll
    for (int c = 0; c < 4; ++c) {
      const bf16x8 pa = *(const bf16x8*)(pb + ql * 272 + (32 * c + 8 * g) * 2);
      const bf16x8 v0 = *(const bf16x8*)(vt + ql * 134 + 32 * c + 8 * g);
      const bf16x8 v1 = *(const bf16x8*)(vt + (16 + ql) * 134 + 32 * c + 8 * g);
      og0 = __builtin_amdgcn_mfma_f32_16x16x32_bf16(pa, v0, og0, 0, 0, 0);
      og1 = __builtin_amdgcn_mfma_f32_16x16x32_bf16(pa, v1, og1, 0, 0, 0);
    }
    __builtin_amdgcn_s_setprio(0);
    // ---- normalize (PV rows are q=4g+r -> shfl inv/c128) and store ----
    u16* aop = qkv_blk + (size_t)(mt * 16 + g * 4) * 768 + 256 + h * 32 + ql;
    #pragma unroll
    for (int r = 0; r < 4; ++r) {
      const float iv = __shfl(inv,  4 * g + r);
      const float cc = __shfl(c128, 4 * g + r);
      aop[(size_t)r * 768]      = fbits(fmaf(cc, v128a, fmaf(ow0[r], iv, og0[r])));
      aop[(size_t)r * 768 + 16] = fbits(fmaf(cc, v128b, fmaf(ow1[r], iv, og1[r])));
    }
  }
}

extern "C" void kernel_launch(void* const* d_in, const int* in_sizes, int n_in,
                              void* d_out, int out_size, void* d_ws, size_t ws_size,
                              hipStream_t stream) {
  (void)in_sizes; (void)n_in; (void)out_size; (void)ws_size;
  const float* x      = (const float*)d_in[0];
  const int*   mask   = (const int*)  d_in[1];
  const float* ef     = (const float*)d_in[2];
  const float* w_qkv  = (const float*)d_in[3];
  const float* b_qkv  = (const float*)d_in[4];
  const float* w_proj = (const float*)d_in[5];
  const float* b_proj = (const float*)d_in[6];
  const float* w_gate = (const float*)d_in[7];
  const float* b_gate = (const float*)d_in[8];
  float* out = (float*)d_out;
  char* ws = (char*)d_ws;

  // workspace layout (bytes), total 135,790,592 (<= proven 136,052,736)
  u16* qkv = (u16*)(ws);                     //   101,449,728
  s16* wtq = (s16*)(ws + 101449728);         //       393,216
  s16* wtp = (s16*)(ws + 101842944);         //       131,072
  u16* xb  = (u16*)(ws + 101974016);         //    33,816,576 (dead after QKV GEMM)
  u16* g4t = (u16*)(ws + 101974016);         //    33,554,432 (aliases xb; written after)
  // s4t scratch lives in d_out (4,194,304 B); final GEMM overwrites all of d_out.
  u16* s4t = (u16*)d_out;

  meancvt_kernel<<<B_ * NB_, 256, 0, stream>>>(x, xb);
  wt_kernel<<<(768 * 256 + 256 * 256) / 256, 256, 0, stream>>>(
      w_qkv, w_proj, wtq, wtp);
  mfma_gemm<false, true, 768>
      <<<(B_ * NB_ * KL_ / 128) * 6, 256, 0, stream>>>(
      (const s16*)xb, wtq, b_qkv, qkv);
  pre_kernel<<<(NB_ * BS_ * 32) / 256, 256, 0, stream>>>(
      mask, ef, w_gate, b_gate, g4t, s4t);
  attn_kernel<<<B_ * NB_ * H_, 256, 0, stream>>>(
      qkv, (const u16*)g4t, (const u16*)s4t, w_gate, b_gate);
  mfma_gemm<true, false, 256>
      <<<(B_ * NB_ * BS_ / 128) * 2, 256, 0, stream>>>(
      (const s16*)qkv, wtp, b_proj, out);
}

// Round 19
// 188.435 us; speedup vs baseline: 1.0424x; 1.0055x over previous
//
#include <hip/hip_runtime.h>

#define B_   4
#define NB_  128
#define BS_  128
#define C_   256
#define H_   8
#define KL_  129   // BS_+1
#define SC2_   0.25503486f           // (1/sqrt(32)) * log2(e)
#define LOG2E_ 1.4426950408889634f
#define RSTR_  99072                 // KL_*768: u16 stride of one block in qkv

typedef unsigned short u16;
typedef unsigned int   u32;
typedef short          s16;
typedef __attribute__((ext_vector_type(8))) __bf16 bf16x8;
typedef __attribute__((ext_vector_type(4))) float  f32x4;

__device__ __forceinline__ float bf16tof(u16 u) {
  union { u32 i; float f; } v; v.i = ((u32)u) << 16; return v.f;
}
__device__ __forceinline__ u16 fbits(float a) {
  union { __bf16 h; u16 u; } v; v.h = (__bf16)a; return v.u;
}
__device__ __forceinline__ u32 pk2(float a, float b) {
  union { __bf16 h[2]; u32 u; } v;
  v.h[0] = (__bf16)a; v.h[1] = (__bf16)b;
  return v.u;
}
__device__ __forceinline__ float asf(u32 u) {
  union { u32 i; float f; } v; v.i = u; return v.f;
}

__device__ __forceinline__ void glds16(const void* g, void* l) {
  __builtin_amdgcn_global_load_lds(
      (const __attribute__((address_space(1))) unsigned int*)g,
      (__attribute__((address_space(3))) unsigned int*)l, 16, 0, 0);
}

// ---------- kernel 1: fused per-block mean + f32->bf16 convert ----------
__global__ __launch_bounds__(256) void meancvt_kernel(const float* __restrict__ x,
                                                      u16* __restrict__ xb) {
  const int blk = blockIdx.x;
  const int c = threadIdx.x;
  const float* p = x + (size_t)blk * BS_ * C_ + c;
  u16* q = xb + (size_t)blk * (KL_ * C_) + c;
  float s = 0.f;
  #pragma unroll 4
  for (int r = 0; r < BS_; ++r) {
    const float v = p[(size_t)r * C_];
    s += v;
    q[(size_t)r * C_] = fbits(v);
  }
  q[(size_t)BS_ * C_] = fbits(s * (1.0f / BS_));
}

// ---------- kernel 2: transpose+convert weights ----------
__global__ __launch_bounds__(256) void wt_kernel(const float* __restrict__ wq,
      const float* __restrict__ wp, s16* __restrict__ wtq, s16* __restrict__ wtp) {
  const int i = blockIdx.x * 256 + threadIdx.x;
  if (i < 768 * 256) {
    const int nn = i >> 8, k = i & 255;
    wtq[i] = (s16)fbits(wq[k * 768 + nn]);
  } else {
    const int j = i - 768 * 256;
    const int nn = j >> 8, k = j & 255;
    wtp[j] = (s16)fbits(wp[k * 256 + nn]);
  }
}

// ---------- kernel 4: gate/sadd table precompute ----------
// g4t[n][h][q][k<128] = bf16 gate coeff (mask/diag baked; 0 when masked).
// s4t[n][q][k<128]    = bf16 (e3*log2e; -1e30 when masked). s4t lives in
// d_out scratch (overwritten by the final GEMM). Key 128 handled in attn.
__global__ __launch_bounds__(256) void pre_kernel(const int* __restrict__ mask,
      const float* __restrict__ ef, const float* __restrict__ wg_,
      const float* __restrict__ bg, u16* __restrict__ g4t,
      u16* __restrict__ s4t) {
  const int t = blockIdx.x * 256 + threadIdx.x;   // (n*128+q)*32 + kq
  const int kq = t & 31;
  const int row = t >> 5;                          // n*128+q
  const int n = row >> 7;
  const int q = row & 127;
  const int key0 = kq * 4;
  const int* mrow = mask + (size_t)row * KL_;
  const float* erow = ef + (size_t)row * KL_ * 4;
  float e0[4], e1[4], e2[4], e3[4];
  int m[4];
  #pragma unroll
  for (int r = 0; r < 4; ++r) {
    const int key = key0 + r;
    m[r] = mrow[key];
    float4 ev = *(const float4*)(erow + (size_t)key * 4);
    if (key == q) { ev.x = 0.f; ev.y = 0.f; ev.z = 0.f; ev.w = 1.f; }
    e0[r] = ev.x; e1[r] = ev.y; e2[r] = ev.z; e3[r] = ev.w;
  }
  float s[4];
  #pragma unroll
  for (int r = 0; r < 4; ++r) s[r] = m[r] ? e3[r] * LOG2E_ : -1e30f;
  *(uint2*)(s4t + (size_t)row * 128 + key0) =
      uint2{pk2(s[0], s[1]), pk2(s[2], s[3])};
  #pragma unroll
  for (int h = 0; h < 8; ++h) {
    const float w0 = wg_[h], w1 = wg_[8 + h], w2 = wg_[16 + h],
                w3 = wg_[24 + h], bh = bg[h];
    float gt[4];
    #pragma unroll
    for (int r = 0; r < 4; ++r) {
      const float gg = fmaf(e0[r], w0, fmaf(e1[r], w1,
                        fmaf(e2[r], w2, fmaf(e3[r], w3, bh))));
      gt[r] = m[r] ? gg : 0.f;
    }
    *(uint2*)(g4t + (((size_t)n * 8 + h) * 128 + q) * 128 + key0) =
        uint2{pk2(gt[0], gt[1]), pk2(gt[2], gt[3])};
  }
}

// ---------- kernels 3 & 6: MFMA bf16 GEMM, 2-phase dbuf, XCD-swizzled ------
// 1D grid, nwg % 8 == 0; g=(bid&7)*(nwg/8)+(bid>>3): each XCD owns a
// contiguous row range, ncol column-tiles of a row consecutive on one XCD
// -> A-panel fetched from HBM once, L2-hit (ncol-1)x.
// STRIDED: A bf16 from qkv K-plane: row -> qkv + row*RSTR_ + r*768 + 256.
template<bool STRIDED, bool OBF16, int NS>
__global__ __launch_bounds__(256) void mfma_gemm(const s16* __restrict__ Ab,
      const s16* __restrict__ Bt, const float* __restrict__ bias,
      void* __restrict__ outv) {
  __shared__ __align__(16) s16 Al[2][128 * 64];
  __shared__ __align__(16) s16 Bl[2][128 * 64];
  const int tid = threadIdx.x;
  const int lane = tid & 63;
  const int wid = tid >> 6;
  constexpr int ncol = NS / 128;
  const int per  = gridDim.x >> 3;
  const int gidx = (blockIdx.x & 7) * per + (blockIdx.x >> 3);
  const int arow = gidx / ncol;
  const int col0 = (gidx - arow * ncol) * 128;
  const int row0 = arow * 128;
  const int ldrow = lane >> 3;
  const int lcb   = (lane & 7) * 16;

  auto STAGE = [&](int k0, int buf) {
    #pragma unroll
    for (int j = 0; j < 4; ++j) {
      const int c = wid * 4 + j;
      const int row = c * 8 + ldrow;
      const int scb = lcb ^ ((row & 7) << 4);
      glds16(Bt + (size_t)(col0 + row) * C_ + k0 + (scb >> 1), &Bl[buf][c * 512]);
    }
    #pragma unroll
    for (int j = 0; j < 4; ++j) {
      const int c = wid * 4 + j;
      const int row = c * 8 + ldrow;
      const int scb = lcb ^ ((row & 7) << 4);
      if constexpr (STRIDED)
        glds16(Ab + (size_t)arow * RSTR_ + (size_t)row * 768 + 256
                  + k0 + (scb >> 1), &Al[buf][c * 512]);
      else
        glds16(Ab + (size_t)(row0 + row) * C_ + k0 + (scb >> 1), &Al[buf][c * 512]);
    }
  };

  f32x4 acc[4][4];
  #pragma unroll
  for (int i = 0; i < 4; ++i)
    #pragma unroll
    for (int j = 0; j < 4; ++j) acc[i][j] = f32x4{0.f, 0.f, 0.f, 0.f};

  STAGE(0, 0);
  __syncthreads();

  const int fr = lane & 15;
  const int ar0 = (wid >> 1) * 64;
  const int ac0 = (wid & 1) * 64;
  #pragma unroll 1
  for (int t = 0; t < 4; ++t) {
    if (t < 3) STAGE((t + 1) * 64, (t + 1) & 1);
    const char* Ac = (const char*)&Al[t & 1][0];
    const char* Bc = (const char*)&Bl[t & 1][0];
    #pragma unroll
    for (int kk = 0; kk < 64; kk += 32) {
      const int kb = kk * 2 + (lane >> 4) * 16;
      bf16x8 af[4], bfr[4];
      #pragma unroll
      for (int mf = 0; mf < 4; ++mf) {
        const int row = ar0 + mf * 16 + fr;
        af[mf] = *(const bf16x8*)(Ac + row * 128 + (kb ^ ((row & 7) << 4)));
      }
      #pragma unroll
      for (int nf = 0; nf < 4; ++nf) {
        const int row = ac0 + nf * 16 + fr;
        bfr[nf] = *(const bf16x8*)(Bc + row * 128 + (kb ^ ((row & 7) << 4)));
      }
      #pragma unroll
      for (int mf = 0; mf < 4; ++mf)
        #pragma unroll
        for (int nf = 0; nf < 4; ++nf)
          acc[mf][nf] = __builtin_amdgcn_mfma_f32_16x16x32_bf16(
              af[mf], bfr[nf], acc[mf][nf], 0, 0, 0);
    }
    __syncthreads();
  }

  const int orow0 = row0 + (wid >> 1) * 64 + (lane >> 4) * 4;
  const int ocol0 = col0 + (wid & 1) * 64 + (lane & 15);
  #pragma unroll
  for (int nf = 0; nf < 4; ++nf) {
    const int col = ocol0 + nf * 16;
    const float bb = bias[col];
    #pragma unroll
    for (int mf = 0; mf < 4; ++mf) {
      #pragma unroll
      for (int r = 0; r < 4; ++r) {
        const size_t row = (size_t)(orow0 + mf * 16 + r);
        const float v = acc[mf][nf][r] + bb;
        if constexpr (OBF16) ((u16*)outv)[row * NS + col] = fbits(v);
        else                 ((float*)outv)[row * NS + col] = v;
      }
    }
  }
}

// ---------- kernel 5: MFMA fused block attention (round-18 + qf prefetch) --
// One WG per (block, head), h WG-uniform; XCD-aware swizzle. 4 waves;
// K[129][40], V^T[32][134] staged cooperatively; wave wid owns mt tiles
// {2wid, 2wid+1}; two-phase PV with setprio around MFMA clusters.
// NEW: both mt iterations' qf fragments are loaded up front (Q-plane is
// never written; outputs go to the K-plane), removing the second serial
// ~300cy L2 round-trip per wave; mt loop fully unrolled so qf selection
// is static (rule #20).
__global__ __launch_bounds__(256, 4) void attn_kernel(u16* __restrict__ qkv,
      const u16* __restrict__ g4t, const u16* __restrict__ s4t,
      const float* __restrict__ wg_, const float* __restrict__ bg) {
  __shared__ __align__(16) char lds[36304];  // K 10320 + V^T 8576 + 4x P 4352
  const int bid = blockIdx.x;
  const int xcd = bid & 7;
  const int j   = bid >> 3;                  // 0..511
  const int wgi = xcd * 64 + (j >> 3);       // b*NB_ + n  (64 blocks per XCD)
  const int h   = j & 7;                     // WG-uniform head
  const int n = wgi & (NB_ - 1);
  const int tid = threadIdx.x;
  const int wid = tid >> 6, lane = tid & 63;
  const int g = lane >> 4, ql = lane & 15;
  u16*  Kl = (u16*)lds;                      // [129][40] u16 (rows padded)
  u16*  vt = (u16*)(lds + 10320);            // [32 d][134 keys] u16
  char* pb = lds + 18896 + wid * 4352;       // per-wave P: 16 rows x 272 B

  u16* qkv_blk = qkv + (size_t)wgi * RSTR_;
  const u16* sbase = s4t + (size_t)n * (128 * 128);
  const u16* gbase = g4t + ((size_t)n * 8 + h) * (128 * 128);

  // cooperative stage: K rows (64B each) into padded LDS rows
  for (int i = tid; i < 516; i += 256) {
    const int r = i >> 2, dc = i & 3;
    const uint4 u = *(const uint4*)(qkv_blk + (size_t)r * 768 + 256 + h * 32 + dc * 8);
    *(uint4*)(Kl + r * 40 + dc * 8) = u;
  }
  // cooperative stage: V^T keys 0..127 (transposed scalar writes)
  for (int i = tid; i < 512; i += 256) {
    const int r = i >> 2, dc = i & 3;
    const uint4 u = *(const uint4*)(qkv_blk + (size_t)r * 768 + 512 + h * 32 + dc * 8);
    u16* col = vt + (dc * 8) * 134 + r;
    col[0 * 134] = (u16)(u.x & 0xffff); col[1 * 134] = (u16)(u.x >> 16);
    col[2 * 134] = (u16)(u.y & 0xffff); col[3 * 134] = (u16)(u.y >> 16);
    col[4 * 134] = (u16)(u.z & 0xffff); col[5 * 134] = (u16)(u.z >> 16);
    col[6 * 134] = (u16)(u.w & 0xffff); col[7 * 134] = (u16)(u.w >> 16);
  }

  // key-128 V values + both mts' Q fragments (Q-plane is read-only)
  const float v128a = bf16tof(qkv_blk[(size_t)128 * 768 + 512 + h * 32 + ql]);
  const float v128b = bf16tof(qkv_blk[(size_t)128 * 768 + 512 + h * 32 + 16 + ql]);
  const float gk128 = wg_[24 + h] + bg[h];   // key-128 gate (always unmasked)
  const bf16x8 qf0 = *(const bf16x8*)(
      qkv_blk + (size_t)(wid * 32 + ql) * 768 + h * 32 + g * 8);
  const bf16x8 qf1 = *(const bf16x8*)(
      qkv_blk + (size_t)(wid * 32 + 16 + ql) * 768 + h * 32 + g * 8);
  __syncthreads();

  #pragma unroll
  for (int mi = 0; mi < 2; ++mi) {
    const int mt = wid * 2 + mi;
    const int qrow = mt * 16 + ql;
    const bf16x8 qf = (mi == 0) ? qf0 : qf1;
    const u16* srow = sbase + (size_t)qrow * 128;
    const u16* grow = gbase + (size_t)qrow * 128;

    // ---- phase A: stream f; write UNNORMALIZED w to P; stash gate words ----
    float psum = 0.f;
    uint2 gab[8];
    #pragma unroll
    for (int f = 0; f < 8; ++f) {
      const bf16x8 kf = *(const bf16x8*)(Kl + (16 * f + ql) * 40 + 8 * g);
      f32x4 st = __builtin_amdgcn_mfma_f32_16x16x32_bf16(
          kf, qf, f32x4{0.f, 0.f, 0.f, 0.f}, 0, 0, 0);
      const uint2 sv = *(const uint2*)(srow + 16 * f + 4 * g);
      gab[f] = *(const uint2*)(grow + 16 * f + 4 * g);
      float w[4];
      w[0] = __builtin_amdgcn_exp2f(fmaf(st[0], SC2_, asf(sv.x << 16)));
      w[1] = __builtin_amdgcn_exp2f(fmaf(st[1], SC2_, asf(sv.x & 0xffff0000u)));
      w[2] = __builtin_amdgcn_exp2f(fmaf(st[2], SC2_, asf(sv.y << 16)));
      w[3] = __builtin_amdgcn_exp2f(fmaf(st[3], SC2_, asf(sv.y & 0xffff0000u)));
      psum += (w[0] + w[1]) + (w[2] + w[3]);
      *(uint2*)(pb + ql * 272 + (16 * f + 4 * g) * 2) =
          uint2{pk2(w[0], w[1]), pk2(w[2], w[3])};
    }
    // key 128 (always unmasked; broadcast row read)
    const bf16x8 kf8 = *(const bf16x8*)(Kl + 128 * 40 + 8 * g);
    f32x4 st8 = __builtin_amdgcn_mfma_f32_16x16x32_bf16(
        kf8, qf, f32x4{0.f, 0.f, 0.f, 0.f}, 0, 0, 0);
    const float w0 = __builtin_amdgcn_exp2f(
        fmaf(st8[0], SC2_, (g == 0) ? LOG2E_ : -1e30f));
    psum += w0;
    psum += __shfl_xor(psum, 16);
    psum += __shfl_xor(psum, 32);
    const float inv = __builtin_amdgcn_rcpf(psum);
    const float c128 = fmaf(w0, inv, (g == 0) ? gk128 : 0.f);

    // ---- PV over unnormalized w (pure MFMA cluster: setprio) ----
    f32x4 ow0{0.f,0.f,0.f,0.f}, ow1{0.f,0.f,0.f,0.f};
    __builtin_amdgcn_s_setprio(1);
    #pragma unroll
    for (int c = 0; c < 4; ++c) {
      const bf16x8 pa = *(const bf16x8*)(pb + ql * 272 + (32 * c + 8 * g) * 2);
      const bf16x8 v0 = *(const bf16x8*)(vt + ql * 134 + 32 * c + 8 * g);
      const bf16x8 v1 = *(const bf16x8*)(vt + (16 + ql) * 134 + 32 * c + 8 * g);
      ow0 = __builtin_amdgcn_mfma_f32_16x16x32_bf16(pa, v0, ow0, 0, 0, 0);
      ow1 = __builtin_amdgcn_mfma_f32_16x16x32_bf16(pa, v1, ow1, 0, 0, 0);
    }
    __builtin_amdgcn_s_setprio(0);
    // ---- phase B: gate pass through the same P tile (prepacked words) ----
    #pragma unroll
    for (int f = 0; f < 8; ++f)
      *(uint2*)(pb + ql * 272 + (16 * f + 4 * g) * 2) = gab[f];
    f32x4 og0{0.f,0.f,0.f,0.f}, og1{0.f,0.f,0.f,0.f};
    __builtin_amdgcn_s_setprio(1);
    #pragma unroll
    for (int c = 0; c < 4; ++c) {
      const bf16x8 pa = *(const bf16x8*)(pb + ql * 272 + (32 * c + 8 * g) * 2);
      const bf16x8 v0 = *(const bf16x8*)(vt + ql * 134 + 32 * c + 8 * g);
      const bf16x8 v1 = *(const bf16x8*)(vt + (16 + ql) * 134 + 32 * c + 8 * g);
      og0 = __builtin_amdgcn_mfma_f32_16x16x32_bf16(pa, v0, og0, 0, 0, 0);
      og1 = __builtin_amdgcn_mfma_f32_16x16x32_bf16(pa, v1, og1, 0, 0, 0);
    }
    __builtin_amdgcn_s_setprio(0);
    // ---- normalize (PV rows are q=4g+r -> shfl inv/c128) and store ----
    u16* aop = qkv_blk + (size_t)(mt * 16 + g * 4) * 768 + 256 + h * 32 + ql;
    #pragma unroll
    for (int r = 0; r < 4; ++r) {
      const float iv = __shfl(inv,  4 * g + r);
      const float cc = __shfl(c128, 4 * g + r);
      aop[(size_t)r * 768]      = fbits(fmaf(cc, v128a, fmaf(ow0[r], iv, og0[r])));
      aop[(size_t)r * 768 + 16] = fbits(fmaf(cc, v128b, fmaf(ow1[r], iv, og1[r])));
    }
  }
}

extern "C" void kernel_launch(void* const* d_in, const int* in_sizes, int n_in,
                              void* d_out, int out_size, void* d_ws, size_t ws_size,
                              hipStream_t stream) {
  (void)in_sizes; (void)n_in; (void)out_size; (void)ws_size;
  const float* x      = (const float*)d_in[0];
  const int*   mask   = (const int*)  d_in[1];
  const float* ef     = (const float*)d_in[2];
  const float* w_qkv  = (const float*)d_in[3];
  const float* b_qkv  = (const float*)d_in[4];
  const float* w_proj = (const float*)d_in[5];
  const float* b_proj = (const float*)d_in[6];
  const float* w_gate = (const float*)d_in[7];
  const float* b_gate = (const float*)d_in[8];
  float* out = (float*)d_out;
  char* ws = (char*)d_ws;

  // workspace layout (bytes), total 135,790,592 (<= proven 136,052,736)
  u16* qkv = (u16*)(ws);                     //   101,449,728
  s16* wtq = (s16*)(ws + 101449728);         //       393,216
  s16* wtp = (s16*)(ws + 101842944);         //       131,072
  u16* xb  = (u16*)(ws + 101974016);         //    33,816,576 (dead after QKV GEMM)
  u16* g4t = (u16*)(ws + 101974016);         //    33,554,432 (aliases xb; written after)
  // s4t scratch lives in d_out (4,194,304 B); final GEMM overwrites all of d_out.
  u16* s4t = (u16*)d_out;

  meancvt_kernel<<<B_ * NB_, 256, 0, stream>>>(x, xb);
  wt_kernel<<<(768 * 256 + 256 * 256) / 256, 256, 0, stream>>>(
      w_qkv, w_proj, wtq, wtp);
  mfma_gemm<false, true, 768>
      <<<(B_ * NB_ * KL_ / 128) * 6, 256, 0, stream>>>(
      (const s16*)xb, wtq, b_qkv, qkv);
  pre_kernel<<<(NB_ * BS_ * 32) / 256, 256, 0, stream>>>(
      mask, ef, w_gate, b_gate, g4t, s4t);
  attn_kernel<<<B_ * NB_ * H_, 256, 0, stream>>>(
      qkv, (const u16*)g4t, (const u16*)s4t, w_gate, b_gate);
  mfma_gemm<true, false, 256>
      <<<(B_ * NB_ * BS_ / 128) * 2, 256, 0, stream>>>(
      (const s16*)qkv, wtp, b_proj, out);
}

// Round 20
// 186.820 us; speedup vs baseline: 1.0515x; 1.0086x over previous
//
#include <hip/hip_runtime.h>

#define B_   4
#define NB_  128
#define BS_  128
#define C_   256
#define H_   8
#define KL_  129   // BS_+1
#define SC2_   0.25503486f           // (1/sqrt(32)) * log2(e)
#define LOG2E_ 1.4426950408889634f
#define RSTR_  99072                 // KL_*768: u16 stride of one block in qkv

typedef unsigned short u16;
typedef unsigned int   u32;
typedef short          s16;
typedef __attribute__((ext_vector_type(8))) __bf16 bf16x8;
typedef __attribute__((ext_vector_type(4))) float  f32x4;

__device__ __forceinline__ float bf16tof(u16 u) {
  union { u32 i; float f; } v; v.i = ((u32)u) << 16; return v.f;
}
__device__ __forceinline__ u16 fbits(float a) {
  union { __bf16 h; u16 u; } v; v.h = (__bf16)a; return v.u;
}
__device__ __forceinline__ u32 pk2(float a, float b) {
  union { __bf16 h[2]; u32 u; } v;
  v.h[0] = (__bf16)a; v.h[1] = (__bf16)b;
  return v.u;
}
__device__ __forceinline__ float asf(u32 u) {
  union { u32 i; float f; } v; v.i = u; return v.f;
}

__device__ __forceinline__ void glds16(const void* g, void* l) {
  __builtin_amdgcn_global_load_lds(
      (const __attribute__((address_space(1))) unsigned int*)g,
      (__attribute__((address_space(3))) unsigned int*)l, 16, 0, 0);
}

// ---------- kernel 1: fused per-block mean + f32->bf16 convert ----------
__global__ __launch_bounds__(256) void meancvt_kernel(const float* __restrict__ x,
                                                      u16* __restrict__ xb) {
  const int blk = blockIdx.x;
  const int c = threadIdx.x;
  const float* p = x + (size_t)blk * BS_ * C_ + c;
  u16* q = xb + (size_t)blk * (KL_ * C_) + c;
  float s = 0.f;
  #pragma unroll 4
  for (int r = 0; r < BS_; ++r) {
    const float v = p[(size_t)r * C_];
    s += v;
    q[(size_t)r * C_] = fbits(v);
  }
  q[(size_t)BS_ * C_] = fbits(s * (1.0f / BS_));
}

// ---------- kernel 2: transpose+convert weights ----------
__global__ __launch_bounds__(256) void wt_kernel(const float* __restrict__ wq,
      const float* __restrict__ wp, s16* __restrict__ wtq, s16* __restrict__ wtp) {
  const int i = blockIdx.x * 256 + threadIdx.x;
  if (i < 768 * 256) {
    const int nn = i >> 8, k = i & 255;
    wtq[i] = (s16)fbits(wq[k * 768 + nn]);
  } else {
    const int j = i - 768 * 256;
    const int nn = j >> 8, k = j & 255;
    wtp[j] = (s16)fbits(wp[k * 256 + nn]);
  }
}

// ---------- kernel 4: gate/sadd table precompute ----------
// g4t[n][h][q][k<128] = bf16 gate coeff (mask/diag baked; 0 when masked).
// s4t[n][q][k<128]    = bf16 (e3*log2e; -1e30 when masked). s4t lives in
// d_out scratch (overwritten by the final GEMM). Key 128 handled in attn.
__global__ __launch_bounds__(256) void pre_kernel(const int* __restrict__ mask,
      const float* __restrict__ ef, const float* __restrict__ wg_,
      const float* __restrict__ bg, u16* __restrict__ g4t,
      u16* __restrict__ s4t) {
  const int t = blockIdx.x * 256 + threadIdx.x;   // (n*128+q)*32 + kq
  const int kq = t & 31;
  const int row = t >> 5;                          // n*128+q
  const int n = row >> 7;
  const int q = row & 127;
  const int key0 = kq * 4;
  const int* mrow = mask + (size_t)row * KL_;
  const float* erow = ef + (size_t)row * KL_ * 4;
  float e0[4], e1[4], e2[4], e3[4];
  int m[4];
  #pragma unroll
  for (int r = 0; r < 4; ++r) {
    const int key = key0 + r;
    m[r] = mrow[key];
    float4 ev = *(const float4*)(erow + (size_t)key * 4);
    if (key == q) { ev.x = 0.f; ev.y = 0.f; ev.z = 0.f; ev.w = 1.f; }
    e0[r] = ev.x; e1[r] = ev.y; e2[r] = ev.z; e3[r] = ev.w;
  }
  float s[4];
  #pragma unroll
  for (int r = 0; r < 4; ++r) s[r] = m[r] ? e3[r] * LOG2E_ : -1e30f;
  *(uint2*)(s4t + (size_t)row * 128 + key0) =
      uint2{pk2(s[0], s[1]), pk2(s[2], s[3])};
  #pragma unroll
  for (int h = 0; h < 8; ++h) {
    const float w0 = wg_[h], w1 = wg_[8 + h], w2 = wg_[16 + h],
                w3 = wg_[24 + h], bh = bg[h];
    float gt[4];
    #pragma unroll
    for (int r = 0; r < 4; ++r) {
      const float gg = fmaf(e0[r], w0, fmaf(e1[r], w1,
                        fmaf(e2[r], w2, fmaf(e3[r], w3, bh))));
      gt[r] = m[r] ? gg : 0.f;
    }
    *(uint2*)(g4t + (((size_t)n * 8 + h) * 128 + q) * 128 + key0) =
        uint2{pk2(gt[0], gt[1]), pk2(gt[2], gt[3])};
  }
}

// ---------- kernels 3 & 6: MFMA bf16 GEMM, 2-phase dbuf, XCD-swizzled ------
// 1D grid, nwg % 8 == 0; g=(bid&7)*(nwg/8)+(bid>>3): each XCD owns a
// contiguous row range, ncol column-tiles of a row consecutive on one XCD
// -> A-panel fetched from HBM once, L2-hit (ncol-1)x.
// STRIDED: A bf16 from qkv K-plane: row -> qkv + row*RSTR_ + r*768 + 256.
template<bool STRIDED, bool OBF16, int NS>
__global__ __launch_bounds__(256) void mfma_gemm(const s16* __restrict__ Ab,
      const s16* __restrict__ Bt, const float* __restrict__ bias,
      void* __restrict__ outv) {
  __shared__ __align__(16) s16 Al[2][128 * 64];
  __shared__ __align__(16) s16 Bl[2][128 * 64];
  const int tid = threadIdx.x;
  const int lane = tid & 63;
  const int wid = tid >> 6;
  constexpr int ncol = NS / 128;
  const int per  = gridDim.x >> 3;
  const int gidx = (blockIdx.x & 7) * per + (blockIdx.x >> 3);
  const int arow = gidx / ncol;
  const int col0 = (gidx - arow * ncol) * 128;
  const int row0 = arow * 128;
  const int ldrow = lane >> 3;
  const int lcb   = (lane & 7) * 16;

  auto STAGE = [&](int k0, int buf) {
    #pragma unroll
    for (int j = 0; j < 4; ++j) {
      const int c = wid * 4 + j;
      const int row = c * 8 + ldrow;
      const int scb = lcb ^ ((row & 7) << 4);
      glds16(Bt + (size_t)(col0 + row) * C_ + k0 + (scb >> 1), &Bl[buf][c * 512]);
    }
    #pragma unroll
    for (int j = 0; j < 4; ++j) {
      const int c = wid * 4 + j;
      const int row = c * 8 + ldrow;
      const int scb = lcb ^ ((row & 7) << 4);
      if constexpr (STRIDED)
        glds16(Ab + (size_t)arow * RSTR_ + (size_t)row * 768 + 256
                  + k0 + (scb >> 1), &Al[buf][c * 512]);
      else
        glds16(Ab + (size_t)(row0 + row) * C_ + k0 + (scb >> 1), &Al[buf][c * 512]);
    }
  };

  f32x4 acc[4][4];
  #pragma unroll
  for (int i = 0; i < 4; ++i)
    #pragma unroll
    for (int j = 0; j < 4; ++j) acc[i][j] = f32x4{0.f, 0.f, 0.f, 0.f};

  STAGE(0, 0);
  __syncthreads();

  const int fr = lane & 15;
  const int ar0 = (wid >> 1) * 64;
  const int ac0 = (wid & 1) * 64;
  #pragma unroll 1
  for (int t = 0; t < 4; ++t) {
    if (t < 3) STAGE((t + 1) * 64, (t + 1) & 1);
    const char* Ac = (const char*)&Al[t & 1][0];
    const char* Bc = (const char*)&Bl[t & 1][0];
    #pragma unroll
    for (int kk = 0; kk < 64; kk += 32) {
      const int kb = kk * 2 + (lane >> 4) * 16;
      bf16x8 af[4], bfr[4];
      #pragma unroll
      for (int mf = 0; mf < 4; ++mf) {
        const int row = ar0 + mf * 16 + fr;
        af[mf] = *(const bf16x8*)(Ac + row * 128 + (kb ^ ((row & 7) << 4)));
      }
      #pragma unroll
      for (int nf = 0; nf < 4; ++nf) {
        const int row = ac0 + nf * 16 + fr;
        bfr[nf] = *(const bf16x8*)(Bc + row * 128 + (kb ^ ((row & 7) << 4)));
      }
      #pragma unroll
      for (int mf = 0; mf < 4; ++mf)
        #pragma unroll
        for (int nf = 0; nf < 4; ++nf)
          acc[mf][nf] = __builtin_amdgcn_mfma_f32_16x16x32_bf16(
              af[mf], bfr[nf], acc[mf][nf], 0, 0, 0);
    }
    __syncthreads();
  }

  const int orow0 = row0 + (wid >> 1) * 64 + (lane >> 4) * 4;
  const int ocol0 = col0 + (wid & 1) * 64 + (lane & 15);
  #pragma unroll
  for (int nf = 0; nf < 4; ++nf) {
    const int col = ocol0 + nf * 16;
    const float bb = bias[col];
    #pragma unroll
    for (int mf = 0; mf < 4; ++mf) {
      #pragma unroll
      for (int r = 0; r < 4; ++r) {
        const size_t row = (size_t)(orow0 + mf * 16 + r);
        const float v = acc[mf][nf][r] + bb;
        if constexpr (OBF16) ((u16*)outv)[row * NS + col] = fbits(v);
        else                 ((float*)outv)[row * NS + col] = v;
      }
    }
  }
}

// ---------- kernel 5: MFMA fused block attention (round-19 + late gv) ------
// One WG per (block, head), h WG-uniform; XCD-aware swizzle. 4 waves;
// K[129][40], V^T[32][134] staged cooperatively; wave wid owns mt tiles
// {2wid, 2wid+1}; two-phase PV with setprio; qf prefetch for both mts.
// NEW vs r19: gate words are NOT stashed during phase A (-16 live VGPRs in
// the congested phase); the 8 gv loads are issued in a batch right after
// the psum reduce and fly under the PV(w) MFMA cluster, consumed in phase B.
__global__ __launch_bounds__(256, 4) void attn_kernel(u16* __restrict__ qkv,
      const u16* __restrict__ g4t, const u16* __restrict__ s4t,
      const float* __restrict__ wg_, const float* __restrict__ bg) {
  __shared__ __align__(16) char lds[36304];  // K 10320 + V^T 8576 + 4x P 4352
  const int bid = blockIdx.x;
  const int xcd = bid & 7;
  const int j   = bid >> 3;                  // 0..511
  const int wgi = xcd * 64 + (j >> 3);       // b*NB_ + n  (64 blocks per XCD)
  const int h   = j & 7;                     // WG-uniform head
  const int n = wgi & (NB_ - 1);
  const int tid = threadIdx.x;
  const int wid = tid >> 6, lane = tid & 63;
  const int g = lane >> 4, ql = lane & 15;
  u16*  Kl = (u16*)lds;                      // [129][40] u16 (rows padded)
  u16*  vt = (u16*)(lds + 10320);            // [32 d][134 keys] u16
  char* pb = lds + 18896 + wid * 4352;       // per-wave P: 16 rows x 272 B

  u16* qkv_blk = qkv + (size_t)wgi * RSTR_;
  const u16* sbase = s4t + (size_t)n * (128 * 128);
  const u16* gbase = g4t + ((size_t)n * 8 + h) * (128 * 128);

  // cooperative stage: K rows (64B each) into padded LDS rows
  for (int i = tid; i < 516; i += 256) {
    const int r = i >> 2, dc = i & 3;
    const uint4 u = *(const uint4*)(qkv_blk + (size_t)r * 768 + 256 + h * 32 + dc * 8);
    *(uint4*)(Kl + r * 40 + dc * 8) = u;
  }
  // cooperative stage: V^T keys 0..127 (transposed scalar writes)
  for (int i = tid; i < 512; i += 256) {
    const int r = i >> 2, dc = i & 3;
    const uint4 u = *(const uint4*)(qkv_blk + (size_t)r * 768 + 512 + h * 32 + dc * 8);
    u16* col = vt + (dc * 8) * 134 + r;
    col[0 * 134] = (u16)(u.x & 0xffff); col[1 * 134] = (u16)(u.x >> 16);
    col[2 * 134] = (u16)(u.y & 0xffff); col[3 * 134] = (u16)(u.y >> 16);
    col[4 * 134] = (u16)(u.z & 0xffff); col[5 * 134] = (u16)(u.z >> 16);
    col[6 * 134] = (u16)(u.w & 0xffff); col[7 * 134] = (u16)(u.w >> 16);
  }

  // key-128 V values + both mts' Q fragments (Q-plane is read-only)
  const float v128a = bf16tof(qkv_blk[(size_t)128 * 768 + 512 + h * 32 + ql]);
  const float v128b = bf16tof(qkv_blk[(size_t)128 * 768 + 512 + h * 32 + 16 + ql]);
  const float gk128 = wg_[24 + h] + bg[h];   // key-128 gate (always unmasked)
  const bf16x8 qf0 = *(const bf16x8*)(
      qkv_blk + (size_t)(wid * 32 + ql) * 768 + h * 32 + g * 8);
  const bf16x8 qf1 = *(const bf16x8*)(
      qkv_blk + (size_t)(wid * 32 + 16 + ql) * 768 + h * 32 + g * 8);
  __syncthreads();

  #pragma unroll
  for (int mi = 0; mi < 2; ++mi) {
    const int mt = wid * 2 + mi;
    const int qrow = mt * 16 + ql;
    const bf16x8 qf = (mi == 0) ? qf0 : qf1;
    const u16* srow = sbase + (size_t)qrow * 128;
    const u16* grow = gbase + (size_t)qrow * 128;

    // ---- phase A: stream f; write UNNORMALIZED w to P (no gate stash) ----
    float psum = 0.f;
    #pragma unroll
    for (int f = 0; f < 8; ++f) {
      const bf16x8 kf = *(const bf16x8*)(Kl + (16 * f + ql) * 40 + 8 * g);
      f32x4 st = __builtin_amdgcn_mfma_f32_16x16x32_bf16(
          kf, qf, f32x4{0.f, 0.f, 0.f, 0.f}, 0, 0, 0);
      const uint2 sv = *(const uint2*)(srow + 16 * f + 4 * g);
      float w[4];
      w[0] = __builtin_amdgcn_exp2f(fmaf(st[0], SC2_, asf(sv.x << 16)));
      w[1] = __builtin_amdgcn_exp2f(fmaf(st[1], SC2_, asf(sv.x & 0xffff0000u)));
      w[2] = __builtin_amdgcn_exp2f(fmaf(st[2], SC2_, asf(sv.y << 16)));
      w[3] = __builtin_amdgcn_exp2f(fmaf(st[3], SC2_, asf(sv.y & 0xffff0000u)));
      psum += (w[0] + w[1]) + (w[2] + w[3]);
      *(uint2*)(pb + ql * 272 + (16 * f + 4 * g) * 2) =
          uint2{pk2(w[0], w[1]), pk2(w[2], w[3])};
    }
    // key 128 (always unmasked; broadcast row read)
    const bf16x8 kf8 = *(const bf16x8*)(Kl + 128 * 40 + 8 * g);
    f32x4 st8 = __builtin_amdgcn_mfma_f32_16x16x32_bf16(
        kf8, qf, f32x4{0.f, 0.f, 0.f, 0.f}, 0, 0, 0);
    const float w0 = __builtin_amdgcn_exp2f(
        fmaf(st8[0], SC2_, (g == 0) ? LOG2E_ : -1e30f));
    psum += w0;
    psum += __shfl_xor(psum, 16);
    psum += __shfl_xor(psum, 32);
    const float inv = __builtin_amdgcn_rcpf(psum);
    const float c128 = fmaf(w0, inv, (g == 0) ? gk128 : 0.f);

    // ---- issue phase-B gate loads now: in flight under PV(w) ----
    uint2 gv[8];
    #pragma unroll
    for (int f = 0; f < 8; ++f)
      gv[f] = *(const uint2*)(grow + 16 * f + 4 * g);

    // ---- PV over unnormalized w (pure MFMA cluster: setprio) ----
    f32x4 ow0{0.f,0.f,0.f,0.f}, ow1{0.f,0.f,0.f,0.f};
    __builtin_amdgcn_s_setprio(1);
    #pragma unroll
    for (int c = 0; c < 4; ++c) {
      const bf16x8 pa = *(const bf16x8*)(pb + ql * 272 + (32 * c + 8 * g) * 2);
      const bf16x8 v0 = *(const bf16x8*)(vt + ql * 134 + 32 * c + 8 * g);
      const bf16x8 v1 = *(const bf16x8*)(vt + (16 + ql) * 134 + 32 * c + 8 * g);
      ow0 = __builtin_amdgcn_mfma_f32_16x16x32_bf16(pa, v0, ow0, 0, 0, 0);
      ow1 = __builtin_amdgcn_mfma_f32_16x16x32_bf16(pa, v1, ow1, 0, 0, 0);
    }
    __builtin_amdgcn_s_setprio(0);
    // ---- phase B: gate pass through the same P tile ----
    #pragma unroll
    for (int f = 0; f < 8; ++f)
      *(uint2*)(pb + ql * 272 + (16 * f + 4 * g) * 2) = gv[f];
    f32x4 og0{0.f,0.f,0.f,0.f}, og1{0.f,0.f,0.f,0.f};
    __builtin_amdgcn_s_setprio(1);
    #pragma unroll
    for (int c = 0; c < 4; ++c) {
      const bf16x8 pa = *(const bf16x8*)(pb + ql * 272 + (32 * c + 8 * g) * 2);
      const bf16x8 v0 = *(const bf16x8*)(vt + ql * 134 + 32 * c + 8 * g);
      const bf16x8 v1 = *(const bf16x8*)(vt + (16 + ql) * 134 + 32 * c + 8 * g);
      og0 = __builtin_amdgcn_mfma_f32_16x16x32_bf16(pa, v0, og0, 0, 0, 0);
      og1 = __builtin_amdgcn_mfma_f32_16x16x32_bf16(pa, v1, og1, 0, 0, 0);
    }
    __builtin_amdgcn_s_setprio(0);
    // ---- normalize (PV rows are q=4g+r -> shfl inv/c128) and store ----
    u16* aop = qkv_blk + (size_t)(mt * 16 + g * 4) * 768 + 256 + h * 32 + ql;
    #pragma unroll
    for (int r = 0; r < 4; ++r) {
      const float iv = __shfl(inv,  4 * g + r);
      const float cc = __shfl(c128, 4 * g + r);
      aop[(size_t)r * 768]      = fbits(fmaf(cc, v128a, fmaf(ow0[r], iv, og0[r])));
      aop[(size_t)r * 768 + 16] = fbits(fmaf(cc, v128b, fmaf(ow1[r], iv, og1[r])));
    }
  }
}

extern "C" void kernel_launch(void* const* d_in, const int* in_sizes, int n_in,
                              void* d_out, int out_size, void* d_ws, size_t ws_size,
                              hipStream_t stream) {
  (void)in_sizes; (void)n_in; (void)out_size; (void)ws_size;
  const float* x      = (const float*)d_in[0];
  const int*   mask   = (const int*)  d_in[1];
  const float* ef     = (const float*)d_in[2];
  const float* w_qkv  = (const float*)d_in[3];
  const float* b_qkv  = (const float*)d_in[4];
  const float* w_proj = (const float*)d_in[5];
  const float* b_proj = (const float*)d_in[6];
  const float* w_gate = (const float*)d_in[7];
  const float* b_gate = (const float*)d_in[8];
  float* out = (float*)d_out;
  char* ws = (char*)d_ws;

  // workspace layout (bytes), total 135,790,592 (<= proven 136,052,736)
  u16* qkv = (u16*)(ws);                     //   101,449,728
  s16* wtq = (s16*)(ws + 101449728);         //       393,216
  s16* wtp = (s16*)(ws + 101842944);         //       131,072
  u16* xb  = (u16*)(ws + 101974016);         //    33,816,576 (dead after QKV GEMM)
  u16* g4t = (u16*)(ws + 101974016);         //    33,554,432 (aliases xb; written after)
  // s4t scratch lives in d_out (4,194,304 B); final GEMM overwrites all of d_out.
  u16* s4t = (u16*)d_out;

  meancvt_kernel<<<B_ * NB_, 256, 0, stream>>>(x, xb);
  wt_kernel<<<(768 * 256 + 256 * 256) / 256, 256, 0, stream>>>(
      w_qkv, w_proj, wtq, wtp);
  mfma_gemm<false, true, 768>
      <<<(B_ * NB_ * KL_ / 128) * 6, 256, 0, stream>>>(
      (const s16*)xb, wtq, b_qkv, qkv);
  pre_kernel<<<(NB_ * BS_ * 32) / 256, 256, 0, stream>>>(
      mask, ef, w_gate, b_gate, g4t, s4t);
  attn_kernel<<<B_ * NB_ * H_, 256, 0, stream>>>(
      qkv, (const u16*)g4t, (const u16*)s4t, w_gate, b_gate);
  mfma_gemm<true, false, 256>
      <<<(B_ * NB_ * BS_ / 128) * 2, 256, 0, stream>>>(
      (const s16*)qkv, wtp, b_proj, out);
}